// Round 1
// 167.807 us; speedup vs baseline: 1.0292x; 1.0292x over previous
//
#include <hip/hip_runtime.h>

#define HH 64
#define WW 64
#define S  68          // padded LDS row stride (floats)
#define PH 66          // padded rows (1-px zero frame)
#define NLQ 10
#define NR 8           // rows per thread (512 threads = 8 waves = 2/SIMD)

// One block per image (grid=256 = 1 block/CU). Thread t: column x=t&63, rows
// y0..y0+7. Transition weights (90) + q0 (80) must live in arch VGPRs.
//
// R2/R5/R7 (111us plateau, VGPR_Count=108): the backend budgets VGPRs for the
// occupancy LDS permits (55KB -> 2 blocks/CU -> 4 waves/SIMD -> 512/4 = 128
// budget -> grant 108 arch, demote ~90 regs to AGPRs -> one v_accvgpr_read
// per use = 2x VALU stream). amdgpu_num_vgpr(256) did NOT fix this (it is a
// MAX, not a grant — counters still showed VGPR_Count=108).
//
// R8 fix: pad static LDS past 80KB so only ONE block/CU fits by LDS. The
// heuristic's achievable occupancy is then 2 waves/SIMD no matter the register
// count -> budget 256 unified regs/wave -> the ~200 live values all get arch
// VGPRs, no accvgpr traffic. Grid is 1 block/CU already, so the pad is free.
__global__ __launch_bounds__(512)
__attribute__((amdgpu_waves_per_eu(2, 2)))
void vin_fused(
    const float* __restrict__ X,    // [B,2,64,64]
    const float* __restrict__ Wh,   // [150,2,3,3]
    const float* __restrict__ bh,   // [150]
    const float* __restrict__ Wr,   // [150]
    const float* __restrict__ Wq,   // [10,1,3,3]
    const float* __restrict__ wtr,  // [10,1,3,3] transition
    const float* __restrict__ Wc,   // [4096]
    const float* __restrict__ bc,   // [1]
    float* __restrict__ out)        // [256 critic] ++ [256*40960 q]
{
  __shared__ float vb[2][PH * S];
  __shared__ float rb[PH * S];
  __shared__ float Wef[19];
  __shared__ float Wpart[152];
  __shared__ float Wts[90];
  __shared__ float Wqs[90];
  __shared__ float red[8];
  // Occupancy-budget pad: lifts static LDS to ~83KB (>80KB) so only 1 block/CU
  // fits -> backend budgets 256 VGPRs/wave instead of 128. Never actually
  // written (guard can't be folded: gridDim unknown at compile time).
  __shared__ float lds_pad[7000];

  const int b  = blockIdx.x;
  const int t  = threadIdx.x;
  const int x  = t & 63;
  const int yg = t >> 6;
  const int y0 = yg * NR;
  const int base0 = y0 * S + x;   // top-left of 3x3 window for row y0 (padded)

  if (b == 0x7fffffff) lds_pad[t] = 1.f;   // keep lds_pad allocated

  // ---- zero LDS (frames must be 0; interiors overwritten) ----
  {
    float* vbf = &vb[0][0];
    for (int i = t; i < 2 * PH * S; i += 512) vbf[i] = 0.f;
    for (int i = t; i < PH * S; i += 512) rb[i] = 0.f;
  }
  __syncthreads();

  // ---- stage X into vb interiors; stage weights; collapse 150-ch conv ----
  const float* Xb = X + (size_t)b * (2 * HH * WW);
  for (int i = t; i < HH * WW; i += 512) {
    const int yy = i >> 6, xx = i & 63;
    vb[0][(yy + 1) * S + xx + 1] = Xb[i];
    vb[1][(yy + 1) * S + xx + 1] = Xb[HH * WW + i];
  }
  if (t < 152) {                       // parallel collapse: 19 outputs x 8 parts
    const int i = t >> 3, part = t & 7;
    float s = 0.f;
    if (i < 18) {
      for (int c = part; c < 150; c += 8) s += Wr[c] * Wh[c * 18 + i];
    } else {
      for (int c = part; c < 150; c += 8) s += Wr[c] * bh[c];
    }
    Wpart[t] = s;
  } else if (t >= 256 && t < 346) {
    Wts[t - 256] = wtr[t - 256];
  } else if (t >= 352 && t < 442) {
    Wqs[t - 352] = Wq[t - 352];
  }
  __syncthreads();
  if (t < 19) {
    float s = 0.f;
#pragma unroll
    for (int k = 0; k < 8; ++k) s += Wpart[t * 8 + k];
    Wef[t] = s;
  }
  __syncthreads();

  // ---- r = conv(X, Weff, pad=1) + beff -> rb ----
  {
    float We[19];
#pragma unroll
    for (int i = 0; i < 19; ++i) We[i] = Wef[i];
#pragma unroll
    for (int j = 0; j < NR; ++j) {
      const int tb = base0 + j * S;
      float s = We[18];
#pragma unroll
      for (int dy = 0; dy < 3; ++dy)
#pragma unroll
        for (int dx = 0; dx < 3; ++dx) {
          const int idx = tb + dy * S + dx;
          s = fmaf(vb[0][idx], We[dy * 3 + dx], s);
          s = fmaf(vb[1][idx], We[9 + dy * 3 + dx], s);
        }
      rb[tb + S + 1] = s;
    }
  }
  __syncthreads();

  // ---- q0 = conv(r, Wq, pad=1) -> q0r regs; v_init = max_l q0 -> vb[0] ----
  float q0r[NR][NLQ];
  {
    float m[NR];
#pragma unroll
    for (int l = 0; l < NLQ; ++l) {
      const float w0 = Wqs[l * 9 + 0], w1 = Wqs[l * 9 + 1], w2 = Wqs[l * 9 + 2];
      const float w3 = Wqs[l * 9 + 3], w4 = Wqs[l * 9 + 4], w5 = Wqs[l * 9 + 5];
      const float w6 = Wqs[l * 9 + 6], w7 = Wqs[l * 9 + 7], w8 = Wqs[l * 9 + 8];
#pragma unroll
      for (int j = 0; j < NR; ++j) {
        const int a = base0 + j * S;
        float s;
        s = fmaf(w0, rb[a],             0.f);
        s = fmaf(w1, rb[a + 1],         s);
        s = fmaf(w2, rb[a + 2],         s);
        s = fmaf(w3, rb[a + S],         s);
        s = fmaf(w4, rb[a + S + 1],     s);
        s = fmaf(w5, rb[a + S + 2],     s);
        s = fmaf(w6, rb[a + 2 * S],     s);
        s = fmaf(w7, rb[a + 2 * S + 1], s);
        s = fmaf(w8, rb[a + 2 * S + 2], s);
        q0r[j][l] = s;
        m[j] = (l == 0) ? s : fmaxf(m[j], s);
      }
    }
#pragma unroll
    for (int j = 0; j < NR; ++j) vb[0][base0 + (j + 1) * S + 1] = m[j];
  }
  __syncthreads();

  // ---- K-loop: q = q0 + conv(v, w); v = max_ch(q) ----
  float Wt[90];
#pragma unroll
  for (int i = 0; i < 90; ++i) Wt[i] = Wts[i];

  auto step = [&](const float* __restrict__ vin, float* __restrict__ vout) {
    float a0 = vin[base0],     a1 = vin[base0 + 1],     a2 = vin[base0 + 2];
    float b0 = vin[base0 + S], b1 = vin[base0 + S + 1], b2 = vin[base0 + S + 2];
#pragma unroll
    for (int j = 0; j < NR; ++j) {
      const int rbx = base0 + (j + 2) * S;
      float c0 = vin[rbx], c1 = vin[rbx + 1], c2 = vin[rbx + 2];
      float m;
#pragma unroll
      for (int l = 0; l < NLQ; ++l) {
        float s = q0r[j][l];
        s = fmaf(Wt[l * 9 + 0], a0, s);
        s = fmaf(Wt[l * 9 + 1], a1, s);
        s = fmaf(Wt[l * 9 + 2], a2, s);
        s = fmaf(Wt[l * 9 + 3], b0, s);
        s = fmaf(Wt[l * 9 + 4], b1, s);
        s = fmaf(Wt[l * 9 + 5], b2, s);
        s = fmaf(Wt[l * 9 + 6], c0, s);
        s = fmaf(Wt[l * 9 + 7], c1, s);
        s = fmaf(Wt[l * 9 + 8], c2, s);
        m = (l == 0) ? s : fmaxf(m, s);
      }
      vout[base0 + (j + 1) * S + 1] = m;
      a0 = b0; a1 = b1; a2 = b2;
      b0 = c0; b1 = c1; b2 = c2;
    }
    __syncthreads();
  };

#pragma unroll 1
  for (int s2 = 0; s2 < 19; ++s2) { step(vb[0], vb[1]); step(vb[1], vb[0]); }
  step(vb[0], vb[1]);   // it = 38: reads vb[0], writes vb[1]

  // ---- final iteration (it=39): emit q + critic dot ----
  float wcv[NR];
#pragma unroll
  for (int j = 0; j < NR; ++j) wcv[j] = Wc[(y0 + j) * WW + x];

  float* qo = out + 256 + (size_t)b * (NLQ * HH * WW) + y0 * WW + x;
  float acc = 0.f;
  {
    const float* vin = vb[1];
    float a0 = vin[base0],     a1 = vin[base0 + 1],     a2 = vin[base0 + 2];
    float b0 = vin[base0 + S], b1 = vin[base0 + S + 1], b2 = vin[base0 + S + 2];
#pragma unroll
    for (int j = 0; j < NR; ++j) {
      const int rbx = base0 + (j + 2) * S;
      float c0 = vin[rbx], c1 = vin[rbx + 1], c2 = vin[rbx + 2];
      float m;
#pragma unroll
      for (int l = 0; l < NLQ; ++l) {
        float s = q0r[j][l];
        s = fmaf(Wt[l * 9 + 0], a0, s);
        s = fmaf(Wt[l * 9 + 1], a1, s);
        s = fmaf(Wt[l * 9 + 2], a2, s);
        s = fmaf(Wt[l * 9 + 3], b0, s);
        s = fmaf(Wt[l * 9 + 4], b1, s);
        s = fmaf(Wt[l * 9 + 5], b2, s);
        s = fmaf(Wt[l * 9 + 6], c0, s);
        s = fmaf(Wt[l * 9 + 7], c1, s);
        s = fmaf(Wt[l * 9 + 8], c2, s);
        qo[l * (HH * WW) + j * WW] = s;
        m = (l == 0) ? s : fmaxf(m, s);
      }
      acc = fmaf(m, wcv[j], acc);
      a0 = b0; a1 = b1; a2 = b2;
      b0 = c0; b1 = c1; b2 = c2;
    }
  }

  // ---- block-reduce critic ----
#pragma unroll
  for (int off = 32; off > 0; off >>= 1) acc += __shfl_down(acc, off);
  if (x == 0) red[yg] = acc;
  __syncthreads();
  if (t == 0) {
    float s = bc[0];
#pragma unroll
    for (int i = 0; i < 8; ++i) s += red[i];
    out[b] = s;
  }
}

extern "C" void kernel_launch(void* const* d_in, const int* in_sizes, int n_in,
                              void* d_out, int out_size, void* d_ws, size_t ws_size,
                              hipStream_t stream) {
  (void)n_in; (void)out_size; (void)d_ws; (void)ws_size;
  const float* X   = (const float*)d_in[0];
  const float* Wh  = (const float*)d_in[1];
  const float* bh  = (const float*)d_in[2];
  const float* Wr  = (const float*)d_in[3];
  const float* Wq  = (const float*)d_in[4];
  const float* wtr = (const float*)d_in[5];
  const float* Wc  = (const float*)d_in[6];
  const float* bc  = (const float*)d_in[7];
  float* out = (float*)d_out;

  const int B = in_sizes[0] / (2 * HH * WW);   // 256
  vin_fused<<<B, 512, 0, stream>>>(X, Wh, bh, Wr, Wq, wtr, Wc, bc, out);
}